// Round 4
// baseline (270.714 us; speedup 1.0000x reference)
//
#include <hip/hip_runtime.h>
#include <hip/hip_bf16.h>

typedef __attribute__((ext_vector_type(8))) short bf16x8;
typedef __attribute__((ext_vector_type(4))) float f32x4;

#define NEG_SLOPE 0.2f

__device__ __forceinline__ float bf2f(ushort u){ unsigned x=((unsigned)u)<<16; float f; __builtin_memcpy(&f,&x,4); return f; }
__device__ __forceinline__ ushort f2bf(float f){ __hip_bfloat16 h=__float2bfloat16(f); ushort u; __builtin_memcpy(&u,&h,2); return u; }
__device__ __forceinline__ float bflo(unsigned u){ return bf2f((ushort)(u&0xffffu)); }
__device__ __forceinline__ float bfhi(unsigned u){ return bf2f((ushort)(u>>16)); }
__device__ __forceinline__ float lrelu(float v){ return fmaxf(v,0.f) + NEG_SLOPE*fminf(v,0.f); }

// ---------------- K0: build Wt[256][128] = [Wl|Wr]^T  (f32 -> bf16) ----------------
__global__ __launch_bounds__(256) void k_twt(const float* __restrict__ Wl, const float* __restrict__ Wr,
                                             ushort* __restrict__ Wt)
{
    int idx = blockIdx.x*256 + threadIdx.x;      // 0..32767
    if (idx >= 256*128) return;
    int c = idx >> 7, k = idx & 127;
    float v = (c < 128) ? Wl[k*128 + c] : Wr[k*128 + (c-128)];
    Wt[idx] = f2bf(v);
}

// ---------------- K1: MFMA GEMM  xl|xr = x @ [Wl|Wr] + [bl|br] ----------------
__global__ __launch_bounds__(256) void k_gemm(const float* __restrict__ x, const ushort* __restrict__ Wt,
                                              const float* __restrict__ bl, const float* __restrict__ br,
                                              ushort* __restrict__ xl, ushort* __restrict__ xr, int Nn)
{
    __shared__ ushort As[64*128];                 // 16KB bf16, XOR-swizzled 16B granules
    int tid = threadIdx.x;
    int wave = tid >> 6, lane = tid & 63;
    int l15 = lane & 15, l4 = lane >> 4;
    int row0 = blockIdx.x * 64;

    #pragma unroll
    for (int it = 0; it < 4; ++it) {
        int idx = tid + it*256;                   // granule id (8 cols each), 1024 total
        int r = idx >> 4;
        int g = idx & 15;
        float4 a = make_float4(0,0,0,0), b = make_float4(0,0,0,0);
        int g_row = row0 + r;
        if (g_row < Nn) {
            const float* p = x + (size_t)g_row*128 + g*8;
            a = *(const float4*)p;
            b = *(const float4*)(p + 4);
        }
        union { ushort us[8]; uint4 v; } P;
        P.us[0]=f2bf(a.x); P.us[1]=f2bf(a.y); P.us[2]=f2bf(a.z); P.us[3]=f2bf(a.w);
        P.us[4]=f2bf(b.x); P.us[5]=f2bf(b.y); P.us[6]=f2bf(b.z); P.us[7]=f2bf(b.w);
        int sw = (g*16) ^ ((r & 7) << 4);
        *(uint4*)((char*)As + r*256 + sw) = P.v;
    }
    __syncthreads();

    bf16x8 bfrag[4][4];
    #pragma unroll
    for (int nf = 0; nf < 4; ++nf) {
        int col = wave*64 + nf*16 + l15;
        const ushort* bp = Wt + (size_t)col*128;
        #pragma unroll
        for (int ks = 0; ks < 4; ++ks)
            bfrag[ks][nf] = *(const bf16x8*)(bp + ks*32 + l4*8);
    }
    f32x4 acc[4][4];
    #pragma unroll
    for (int i=0;i<4;++i)
        #pragma unroll
        for (int j=0;j<4;++j) acc[i][j] = (f32x4){0.f,0.f,0.f,0.f};

    #pragma unroll
    for (int ks = 0; ks < 4; ++ks) {
        bf16x8 afrag[4];
        #pragma unroll
        for (int mf = 0; mf < 4; ++mf) {
            int r = mf*16 + l15;
            int kbyte = ks*64 + l4*16;
            afrag[mf] = *(const bf16x8*)((char*)As + r*256 + (kbyte ^ ((r&7)<<4)));
        }
        #pragma unroll
        for (int mf = 0; mf < 4; ++mf)
            #pragma unroll
            for (int nf = 0; nf < 4; ++nf)
                acc[mf][nf] = __builtin_amdgcn_mfma_f32_16x16x32_bf16(afrag[mf], bfrag[ks][nf], acc[mf][nf], 0,0,0);
    }
    #pragma unroll
    for (int mf = 0; mf < 4; ++mf) {
        #pragma unroll
        for (int nf = 0; nf < 4; ++nf) {
            int col = wave*64 + nf*16 + l15;
            float bias = (col < 128) ? bl[col] : br[col-128];
            #pragma unroll
            for (int r = 0; r < 4; ++r) {
                int row = row0 + mf*16 + l4*4 + r;
                if (row < Nn) {
                    ushort o = f2bf(acc[mf][nf][r] + bias);
                    if (col < 128) xl[(size_t)row*128 + col] = o;
                    else           xr[(size_t)row*128 + (col-128)] = o;
                }
            }
        }
    }
}

// ---------------- K2: degree + attr_sum + edge type (atomics) ----------------
__global__ __launch_bounds__(256) void k_deg(const int* __restrict__ dst, const float* __restrict__ ea,
                                             int* __restrict__ deg_i, float* __restrict__ attr_sum,
                                             unsigned char* __restrict__ etype_e, int E)
{
    int e = blockIdx.x*256 + threadIdx.x;
    if (e >= E) return;
    int d = dst[e];
    atomicAdd(&deg_i[d], 1);
    const float* a = ea + (size_t)e*8;
    float4 u0 = *(const float4*)a;
    float4 u1 = *(const float4*)(a + 4);
    float v[8] = {u0.x,u0.y,u0.z,u0.w,u1.x,u1.y,u1.z,u1.w};
    float best = 0.f; int bt = 0;                 // one-hot: find the nonzero component
    #pragma unroll
    for (int j=0;j<8;++j)
        if (fabsf(v[j]) > fabsf(best)) { best = v[j]; bt = j; }
    etype_e[e] = (unsigned char)bt;
    if (best != 0.f) atomicAdd(&attr_sum[(size_t)d*8 + bt], best);
}

// ---------------- scan kernels for CSR offsets ----------------
__global__ __launch_bounds__(256) void k_scan1(const int* __restrict__ deg_i, int* __restrict__ csr_off,
                                               int* __restrict__ partial)
{
    __shared__ int s[256];
    int i = blockIdx.x*256 + threadIdx.x;
    int v = deg_i[i];
    s[threadIdx.x] = v;
    __syncthreads();
    #pragma unroll
    for (int off=1; off<256; off<<=1){
        int t = (threadIdx.x >= off) ? s[threadIdx.x-off] : 0;
        __syncthreads();
        s[threadIdx.x] += t;
        __syncthreads();
    }
    csr_off[i] = s[threadIdx.x] - v;             // exclusive, block-local
    if (threadIdx.x == 255) partial[blockIdx.x] = s[255];
}

__global__ __launch_bounds__(256) void k_scan2(int* __restrict__ partial, int nb)
{
    __shared__ int s[256];
    int t = threadIdx.x;
    int v = (t < nb) ? partial[t] : 0;
    s[t] = v;
    __syncthreads();
    #pragma unroll
    for (int off=1; off<256; off<<=1){
        int u = (t >= off) ? s[t-off] : 0;
        __syncthreads();
        s[t] += u;
        __syncthreads();
    }
    if (t < nb) partial[t] = s[t] - v;           // exclusive block bases
}

__global__ __launch_bounds__(256) void k_scan3(int* __restrict__ csr_off, const int* __restrict__ partial)
{
    int i = blockIdx.x*256 + threadIdx.x;
    csr_off[i] += partial[blockIdx.x];
}

// ---------------- K3: CSR fill, packed src|etype ----------------
__global__ __launch_bounds__(256) void k_fill(const int* __restrict__ src, const int* __restrict__ dst,
                                              const unsigned char* __restrict__ etype_e,
                                              int* __restrict__ cursor, const int* __restrict__ csr_off,
                                              int* __restrict__ csr_pack, int E)
{
    int e = blockIdx.x*256 + threadIdx.x;
    if (e >= E) return;
    int d = dst[e];
    int slot = csr_off[d] + atomicAdd(&cursor[d], 1);
    csr_pack[slot] = src[e] | ((int)etype_e[e] << 24);
}

// ---------------- K4: fused per-node scores + softmax + aggregation + LN + ELU ----------------
// One wave per node; lane owns channels {2*lane, 2*lane+1}; head h = lane/8.
__global__ __launch_bounds__(256) void k_node(const int* __restrict__ deg_i, const int* __restrict__ csr_off,
    const int* __restrict__ csr_pack, const ushort* __restrict__ xl, const ushort* __restrict__ xr,
    const float* __restrict__ We, const float* __restrict__ att, const float* __restrict__ attr_sum,
    const float* __restrict__ bias, const float* __restrict__ lnw, const float* __restrict__ lnb,
    float* __restrict__ out, int Nn)
{
    int wv = threadIdx.x >> 6, lane = threadIdx.x & 63;
    int n = blockIdx.x*4 + wv;
    if (n >= Nn) return;

    unsigned ur = *(const unsigned*)(xr + (size_t)n*128 + lane*2);
    float xr0 = bflo(ur), xr1 = bfhi(ur);
    float2 ap = *(const float2*)(att + lane*2);

    int beg = csr_off[n], cnt = deg_i[n];
    float a0=0.f, a1=0.f, den=0.f;
    #pragma unroll 2
    for (int i=0;i<cnt;++i){
        int packed = csr_pack[beg+i];
        int sidx = packed & 0xFFFFFF;
        int et = packed >> 24;
        unsigned u = *(const unsigned*)(xl + (size_t)sidx*128 + lane*2);
        float x0 = bflo(u), x1 = bfhi(u);
        float2 we = *(const float2*)(We + et*128 + lane*2);
        float p = ap.x*lrelu(x0 + xr0 + we.x) + ap.y*lrelu(x1 + xr1 + we.y);
        p += __shfl_xor(p, 1);
        p += __shfl_xor(p, 2);
        p += __shfl_xor(p, 4);
        float ex = __expf(p);
        a0 += ex*x0; a1 += ex*x1; den += ex;
    }
    // self loop: emb = mean incoming attr @ We, computed wave-parallel
    {
        float inv = 1.f / fmaxf((float)cnt, 1.f);
        float s0 = 0.f, s1 = 0.f;
        #pragma unroll
        for (int t=0;t<8;++t){
            float w = attr_sum[(size_t)n*8 + t] * inv;
            float2 wv = *(const float2*)(We + t*128 + lane*2);
            s0 += w*wv.x; s1 += w*wv.y;
        }
        unsigned u = *(const unsigned*)(xl + (size_t)n*128 + lane*2);
        float x0 = bflo(u), x1 = bfhi(u);
        float p = ap.x*lrelu(x0 + xr0 + s0) + ap.y*lrelu(x1 + xr1 + s1);
        p += __shfl_xor(p, 1);
        p += __shfl_xor(p, 2);
        p += __shfl_xor(p, 4);
        float ex = __expf(p);
        a0 += ex*x0; a1 += ex*x1; den += ex;
    }
    float dinv = 1.f/den;
    {   float2 b = *(const float2*)(bias + lane*2);
        a0 = a0*dinv + b.x; a1 = a1*dinv + b.y;
    }
    float sum = a0 + a1;
    #pragma unroll
    for (int off=32; off>0; off>>=1) sum += __shfl_xor(sum, off);
    float mu = sum * (1.f/128.f);
    float d0 = a0-mu, d1 = a1-mu;
    float vs = d0*d0 + d1*d1;
    #pragma unroll
    for (int off=32; off>0; off>>=1) vs += __shfl_xor(vs, off);
    float rs = rsqrtf(vs*(1.f/128.f) + 1e-5f);
    float2 w = *(const float2*)(lnw + lane*2);
    float2 bb = *(const float2*)(lnb + lane*2);
    float y0 = d0*rs*w.x + bb.x;
    float y1 = d1*rs*w.y + bb.y;
    y0 = (y0 > 0.f) ? y0 : (__expf(y0) - 1.f);
    y1 = (y1 > 0.f) ? y1 : (__expf(y1) - 1.f);
    *(float2*)(out + (size_t)n*128 + lane*2) = make_float2(y0, y1);
}

extern "C" void kernel_launch(void* const* d_in, const int* in_sizes, int n_in,
                              void* d_out, int out_size, void* d_ws, size_t ws_size,
                              hipStream_t stream)
{
    const float* x   = (const float*)d_in[0];
    const int*   src = (const int*)  d_in[1];
    const int*   dst = (const int*)  d_in[2];
    const float* ea  = (const float*)d_in[3];
    const float* Wl  = (const float*)d_in[4];
    const float* bl  = (const float*)d_in[5];
    const float* Wr  = (const float*)d_in[6];
    const float* br  = (const float*)d_in[7];
    const float* We  = (const float*)d_in[8];
    const float* att = (const float*)d_in[9];
    const float* bias= (const float*)d_in[10];
    const float* lnw = (const float*)d_in[11];
    const float* lnb = (const float*)d_in[12];
    float* out = (float*)d_out;

    const int N  = in_sizes[0] / 128;
    const int E  = in_sizes[1];
    const int NP = ((N + 255)/256)*256;
    const int MB = (N + 63)/64;
    const int SB = NP/256;

    char* base = (char*)d_ws;
    size_t o = 0;
    auto alloc = [&](size_t b){ size_t r = o; o += (b + 255) & ~(size_t)255; return r; };
    ushort* Wt       = (ushort*)(base + alloc(256*128*2));
    ushort* xl       = (ushort*)(base + alloc((size_t)MB*64*128*2));
    ushort* xr       = (ushort*)(base + alloc((size_t)MB*64*128*2));
    size_t zoff = o;
    int*    deg_i    = (int*)   (base + alloc((size_t)NP*4));
    int*    cursor   = (int*)   (base + alloc((size_t)NP*4));
    float*  attr_sum = (float*) (base + alloc((size_t)NP*8*4));
    size_t zbytes = o - zoff;
    int*    csr_off  = (int*)   (base + alloc((size_t)NP*4));
    int*    partial  = (int*)   (base + alloc(256*4));
    int*    csr_pack = (int*)   (base + alloc((size_t)E*4));
    unsigned char* etype_e = (unsigned char*)(base + alloc((size_t)E));
    (void)ws_size; (void)n_in; (void)out_size;

    hipMemsetAsync(base + zoff, 0, zbytes, stream);
    k_twt  <<<128, 256, 0, stream>>>(Wl, Wr, Wt);
    k_gemm <<<MB,  256, 0, stream>>>(x, Wt, bl, br, xl, xr, N);
    k_deg  <<<(E+255)/256, 256, 0, stream>>>(dst, ea, deg_i, attr_sum, etype_e, E);
    k_scan1<<<SB,  256, 0, stream>>>(deg_i, csr_off, partial);
    k_scan2<<<1,   256, 0, stream>>>(partial, SB);
    k_scan3<<<SB,  256, 0, stream>>>(csr_off, partial);
    k_fill <<<(E+255)/256, 256, 0, stream>>>(src, dst, etype_e, cursor, csr_off, csr_pack, E);
    k_node <<<(N+3)/4, 256, 0, stream>>>(deg_i, csr_off, csr_pack, xl, xr, We, att, attr_sum,
                                         bias, lnw, lnb, out, N);
}

// Round 5
// 256.107 us; speedup vs baseline: 1.0570x; 1.0570x over previous
//
#include <hip/hip_runtime.h>
#include <hip/hip_bf16.h>

typedef __attribute__((ext_vector_type(8))) short bf16x8;
typedef __attribute__((ext_vector_type(4))) float f32x4;

#define NEG_SLOPE 0.2f

__device__ __forceinline__ float bf2f(ushort u){ unsigned x=((unsigned)u)<<16; float f; __builtin_memcpy(&f,&x,4); return f; }
__device__ __forceinline__ ushort f2bf(float f){ __hip_bfloat16 h=__float2bfloat16(f); ushort u; __builtin_memcpy(&u,&h,2); return u; }
__device__ __forceinline__ float lrelu(float v){ return fmaxf(v,0.f) + NEG_SLOPE*fminf(v,0.f); }

// ---------------- K0: Wt[256][128]=[Wl|Wr]^T (bf16), Web[8][128] (bf16), zero atomics ----------------
__global__ __launch_bounds__(256) void k_twt(const float* __restrict__ Wl, const float* __restrict__ Wr,
                                             const float* __restrict__ We,
                                             ushort* __restrict__ Wt, ushort* __restrict__ Web,
                                             int* __restrict__ zptr, int zn)
{
    int idx = blockIdx.x*256 + threadIdx.x;      // 0..32767
    if (idx < 256*128) {
        int c = idx >> 7, k = idx & 127;
        float v = (c < 128) ? Wl[k*128 + c] : Wr[k*128 + (c-128)];
        Wt[idx] = f2bf(v);
    }
    if (idx < 8*128) Web[idx] = f2bf(We[idx]);
    for (int j = idx; j < zn; j += 128*256) zptr[j] = 0;
}

// ---------------- K1: MFMA GEMM  xl|xr = x @ [Wl|Wr] + [bl|br] ----------------
__global__ __launch_bounds__(256) void k_gemm(const float* __restrict__ x, const ushort* __restrict__ Wt,
                                              const float* __restrict__ bl, const float* __restrict__ br,
                                              ushort* __restrict__ xl, ushort* __restrict__ xr, int Nn)
{
    __shared__ ushort As[64*128];                 // 16KB bf16, XOR-swizzled 16B granules
    int tid = threadIdx.x;
    int wave = tid >> 6, lane = tid & 63;
    int l15 = lane & 15, l4 = lane >> 4;
    int row0 = blockIdx.x * 64;

    #pragma unroll
    for (int it = 0; it < 4; ++it) {
        int idx = tid + it*256;                   // granule id (8 cols each), 1024 total
        int r = idx >> 4;
        int g = idx & 15;
        float4 a = make_float4(0,0,0,0), b = make_float4(0,0,0,0);
        int g_row = row0 + r;
        if (g_row < Nn) {
            const float* p = x + (size_t)g_row*128 + g*8;
            a = *(const float4*)p;
            b = *(const float4*)(p + 4);
        }
        union { ushort us[8]; uint4 v; } P;
        P.us[0]=f2bf(a.x); P.us[1]=f2bf(a.y); P.us[2]=f2bf(a.z); P.us[3]=f2bf(a.w);
        P.us[4]=f2bf(b.x); P.us[5]=f2bf(b.y); P.us[6]=f2bf(b.z); P.us[7]=f2bf(b.w);
        int sw = (g*16) ^ ((r & 7) << 4);
        *(uint4*)((char*)As + r*256 + sw) = P.v;
    }
    __syncthreads();

    bf16x8 bfrag[4][4];
    #pragma unroll
    for (int nf = 0; nf < 4; ++nf) {
        int col = wave*64 + nf*16 + l15;
        const ushort* bp = Wt + (size_t)col*128;
        #pragma unroll
        for (int ks = 0; ks < 4; ++ks)
            bfrag[ks][nf] = *(const bf16x8*)(bp + ks*32 + l4*8);
    }
    f32x4 acc[4][4];
    #pragma unroll
    for (int i=0;i<4;++i)
        #pragma unroll
        for (int j=0;j<4;++j) acc[i][j] = (f32x4){0.f,0.f,0.f,0.f};

    #pragma unroll
    for (int ks = 0; ks < 4; ++ks) {
        bf16x8 afrag[4];
        #pragma unroll
        for (int mf = 0; mf < 4; ++mf) {
            int r = mf*16 + l15;
            int kbyte = ks*64 + l4*16;
            afrag[mf] = *(const bf16x8*)((char*)As + r*256 + (kbyte ^ ((r&7)<<4)));
        }
        #pragma unroll
        for (int mf = 0; mf < 4; ++mf)
            #pragma unroll
            for (int nf = 0; nf < 4; ++nf)
                acc[mf][nf] = __builtin_amdgcn_mfma_f32_16x16x32_bf16(afrag[mf], bfrag[ks][nf], acc[mf][nf], 0,0,0);
    }
    #pragma unroll
    for (int mf = 0; mf < 4; ++mf) {
        #pragma unroll
        for (int nf = 0; nf < 4; ++nf) {
            int col = wave*64 + nf*16 + l15;
            float bias = (col < 128) ? bl[col] : br[col-128];
            #pragma unroll
            for (int r = 0; r < 4; ++r) {
                int row = row0 + mf*16 + l4*4 + r;
                if (row < Nn) {
                    ushort o = f2bf(acc[mf][nf][r] + bias);
                    if (col < 128) xl[(size_t)row*128 + col] = o;
                    else           xr[(size_t)row*128 + (col-128)] = o;
                }
            }
        }
    }
}

// ---------------- K2: degree + attr_sum + edge type (atomics) ----------------
__global__ __launch_bounds__(256) void k_deg(const int* __restrict__ dst, const float* __restrict__ ea,
                                             int* __restrict__ deg_i, float* __restrict__ attr_sum,
                                             unsigned char* __restrict__ etype_e, int E)
{
    int e = blockIdx.x*256 + threadIdx.x;
    if (e >= E) return;
    int d = dst[e];
    atomicAdd(&deg_i[d], 1);
    const float* a = ea + (size_t)e*8;
    float4 u0 = *(const float4*)a;
    float4 u1 = *(const float4*)(a + 4);
    float v[8] = {u0.x,u0.y,u0.z,u0.w,u1.x,u1.y,u1.z,u1.w};
    float best = 0.f; int bt = 0;                 // one-hot: find the nonzero component
    #pragma unroll
    for (int j=0;j<8;++j)
        if (fabsf(v[j]) > fabsf(best)) { best = v[j]; bt = j; }
    etype_e[e] = (unsigned char)bt;
    if (best != 0.f) atomicAdd(&attr_sum[(size_t)d*8 + bt], best);
}

// ---------------- scan kernels for CSR offsets (block-local; bases folded into consumers) ----------------
__global__ __launch_bounds__(256) void k_scan1(const int* __restrict__ deg_i, int* __restrict__ csr_off,
                                               int* __restrict__ partial)
{
    __shared__ int s[256];
    int i = blockIdx.x*256 + threadIdx.x;
    int v = deg_i[i];
    s[threadIdx.x] = v;
    __syncthreads();
    #pragma unroll
    for (int off=1; off<256; off<<=1){
        int t = (threadIdx.x >= off) ? s[threadIdx.x-off] : 0;
        __syncthreads();
        s[threadIdx.x] += t;
        __syncthreads();
    }
    csr_off[i] = s[threadIdx.x] - v;             // exclusive, block-local
    if (threadIdx.x == 255) partial[blockIdx.x] = s[255];
}

__global__ __launch_bounds__(256) void k_scan2(int* __restrict__ partial, int nb)
{
    __shared__ int s[256];
    int t = threadIdx.x;
    int v = (t < nb) ? partial[t] : 0;
    s[t] = v;
    __syncthreads();
    #pragma unroll
    for (int off=1; off<256; off<<=1){
        int u = (t >= off) ? s[t-off] : 0;
        __syncthreads();
        s[t] += u;
        __syncthreads();
    }
    if (t < nb) partial[t] = s[t] - v;           // exclusive block bases
}

// ---------------- K3: CSR fill, packed src|etype (scan base folded in) ----------------
__global__ __launch_bounds__(256) void k_fill(const int* __restrict__ src, const int* __restrict__ dst,
                                              const unsigned char* __restrict__ etype_e,
                                              int* __restrict__ cursor, const int* __restrict__ csr_off,
                                              const int* __restrict__ partial,
                                              int* __restrict__ csr_pack, int E)
{
    int e = blockIdx.x*256 + threadIdx.x;
    if (e >= E) return;
    int d = dst[e];
    int slot = csr_off[d] + partial[d>>8] + atomicAdd(&cursor[d], 1);
    csr_pack[slot] = src[e] | ((int)etype_e[e] << 24);
}

// ---------------- K4: fused per-node pass, 4 edges in flight (16 lanes/edge, 16B/lane) ----------------
// lane: g = lane>>4 (edge slot), l = lane&15 (channel chunk: channels l*8..l*8+7, head l>>1)
__global__ __launch_bounds__(256) void k_node(const int* __restrict__ deg_i, const int* __restrict__ csr_off,
    const int* __restrict__ partial, const int* __restrict__ csr_pack,
    const ushort* __restrict__ xl, const ushort* __restrict__ xr, const ushort* __restrict__ Web,
    const float* __restrict__ att, const float* __restrict__ attr_sum,
    const float* __restrict__ bias, const float* __restrict__ lnw, const float* __restrict__ lnb,
    float* __restrict__ out, int Nn)
{
    int wv = threadIdx.x >> 6, lane = threadIdx.x & 63;
    int n = blockIdx.x*4 + wv;
    if (n >= Nn) return;
    int g = lane >> 4, l = lane & 15;

    // per-lane constants: 8 channels c0 = l*8
    float xrv[8], atv[8], xsv[8];
    {
        bf16x8 r8 = *(const bf16x8*)(xr + (size_t)n*128 + l*8);
        bf16x8 s8 = *(const bf16x8*)(xl + (size_t)n*128 + l*8);
        float4 a0 = *(const float4*)(att + l*8);
        float4 a1 = *(const float4*)(att + l*8 + 4);
        #pragma unroll
        for (int j=0;j<8;++j){ xrv[j] = bf2f((ushort)r8[j]); xsv[j] = bf2f((ushort)s8[j]); }
        atv[0]=a0.x; atv[1]=a0.y; atv[2]=a0.z; atv[3]=a0.w;
        atv[4]=a1.x; atv[5]=a1.y; atv[6]=a1.z; atv[7]=a1.w;
    }

    int beg = csr_off[n] + partial[n>>8];
    int cnt = deg_i[n];
    float acc[8];
    #pragma unroll
    for (int j=0;j<8;++j) acc[j]=0.f;
    float den = 0.f;

    #pragma unroll 2
    for (int i = 0; i < cnt; i += 4) {
        bool valid = (i + g) < cnt;
        int packed = valid ? csr_pack[beg + i + g] : 0;
        int sidx = packed & 0xFFFFFF;
        int et = ((unsigned)packed) >> 24;
        bf16x8 x8 = *(const bf16x8*)(xl + (size_t)sidx*128 + l*8);
        bf16x8 w8 = *(const bf16x8*)(Web + et*128 + l*8);
        float xv[8];
        float p = 0.f;
        #pragma unroll
        for (int j=0;j<8;++j){
            xv[j] = bf2f((ushort)x8[j]);
            p += atv[j]*lrelu(xv[j] + xrv[j] + bf2f((ushort)w8[j]));
        }
        p += __shfl_xor(p, 1);                    // head score (2 lanes/head)
        float ex = valid ? __expf(p) : 0.f;
        den += ex;
        #pragma unroll
        for (int j=0;j<8;++j) acc[j] += ex*xv[j];
    }

    // cross-edge-group reduce: channels identical across the 4 groups after this
    #pragma unroll
    for (int j=0;j<8;++j){
        acc[j] += __shfl_xor(acc[j], 16);
        acc[j] += __shfl_xor(acc[j], 32);
    }
    den += __shfl_xor(den, 16);
    den += __shfl_xor(den, 32);

    // self loop (identical in all lanes of a 16-lane group; groups identical)
    {
        float inv = 1.f / fmaxf((float)cnt, 1.f);
        float e0 = attr_sum[(size_t)n*8+0]*inv, e1 = attr_sum[(size_t)n*8+1]*inv;
        float e2 = attr_sum[(size_t)n*8+2]*inv, e3 = attr_sum[(size_t)n*8+3]*inv;
        float e4 = attr_sum[(size_t)n*8+4]*inv, e5 = attr_sum[(size_t)n*8+5]*inv;
        float e6 = attr_sum[(size_t)n*8+6]*inv, e7 = attr_sum[(size_t)n*8+7]*inv;
        float emb[8];
        #pragma unroll
        for (int j=0;j<8;++j) emb[j]=0.f;
        const ushort* wp = Web + l*8;
        #pragma unroll
        for (int t=0;t<8;++t){
            float w = (t==0)?e0:(t==1)?e1:(t==2)?e2:(t==3)?e3:(t==4)?e4:(t==5)?e5:(t==6)?e6:e7;
            bf16x8 w8 = *(const bf16x8*)(wp + t*128);
            #pragma unroll
            for (int j=0;j<8;++j) emb[j] += w*bf2f((ushort)w8[j]);
        }
        float p = 0.f;
        #pragma unroll
        for (int j=0;j<8;++j) p += atv[j]*lrelu(xsv[j] + xrv[j] + emb[j]);
        p += __shfl_xor(p, 1);
        float ex = __expf(p);
        den += ex;
        #pragma unroll
        for (int j=0;j<8;++j) acc[j] += ex*xsv[j];
    }

    float dinv = 1.f/den;
    float a[8];
    {
        float4 b0 = *(const float4*)(bias + l*8);
        float4 b1 = *(const float4*)(bias + l*8 + 4);
        a[0]=acc[0]*dinv+b0.x; a[1]=acc[1]*dinv+b0.y; a[2]=acc[2]*dinv+b0.z; a[3]=acc[3]*dinv+b0.w;
        a[4]=acc[4]*dinv+b1.x; a[5]=acc[5]*dinv+b1.y; a[6]=acc[6]*dinv+b1.z; a[7]=acc[7]*dinv+b1.w;
    }
    float sum = 0.f;
    #pragma unroll
    for (int j=0;j<8;++j) sum += a[j];
    #pragma unroll
    for (int off=8; off>0; off>>=1) sum += __shfl_xor(sum, off);
    float mu = sum * (1.f/128.f);
    float vs = 0.f;
    #pragma unroll
    for (int j=0;j<8;++j){ a[j] -= mu; vs += a[j]*a[j]; }
    #pragma unroll
    for (int off=8; off>0; off>>=1) vs += __shfl_xor(vs, off);
    float rs = rsqrtf(vs*(1.f/128.f) + 1e-5f);
    float y[8];
    {
        float4 w0 = *(const float4*)(lnw + l*8);
        float4 w1 = *(const float4*)(lnw + l*8 + 4);
        float4 c0 = *(const float4*)(lnb + l*8);
        float4 c1 = *(const float4*)(lnb + l*8 + 4);
        y[0]=a[0]*rs*w0.x+c0.x; y[1]=a[1]*rs*w0.y+c0.y; y[2]=a[2]*rs*w0.z+c0.z; y[3]=a[3]*rs*w0.w+c0.w;
        y[4]=a[4]*rs*w1.x+c1.x; y[5]=a[5]*rs*w1.y+c1.y; y[6]=a[6]*rs*w1.z+c1.z; y[7]=a[7]*rs*w1.w+c1.w;
    }
    #pragma unroll
    for (int j=0;j<8;++j) y[j] = (y[j] > 0.f) ? y[j] : (__expf(y[j]) - 1.f);
    if (lane < 16) {
        float* po = out + (size_t)n*128 + l*8;
        *(float4*)po     = make_float4(y[0],y[1],y[2],y[3]);
        *(float4*)(po+4) = make_float4(y[4],y[5],y[6],y[7]);
    }
}

extern "C" void kernel_launch(void* const* d_in, const int* in_sizes, int n_in,
                              void* d_out, int out_size, void* d_ws, size_t ws_size,
                              hipStream_t stream)
{
    const float* x   = (const float*)d_in[0];
    const int*   src = (const int*)  d_in[1];
    const int*   dst = (const int*)  d_in[2];
    const float* ea  = (const float*)d_in[3];
    const float* Wl  = (const float*)d_in[4];
    const float* bl  = (const float*)d_in[5];
    const float* Wr  = (const float*)d_in[6];
    const float* br  = (const float*)d_in[7];
    const float* We  = (const float*)d_in[8];
    const float* att = (const float*)d_in[9];
    const float* bias= (const float*)d_in[10];
    const float* lnw = (const float*)d_in[11];
    const float* lnb = (const float*)d_in[12];
    float* out = (float*)d_out;

    const int N  = in_sizes[0] / 128;
    const int E  = in_sizes[1];
    const int NP = ((N + 255)/256)*256;
    const int MB = (N + 63)/64;
    const int SB = NP/256;

    char* base = (char*)d_ws;
    size_t o = 0;
    auto alloc = [&](size_t b){ size_t r = o; o += (b + 255) & ~(size_t)255; return r; };
    ushort* Wt       = (ushort*)(base + alloc(256*128*2));
    ushort* Web      = (ushort*)(base + alloc(8*128*2));
    ushort* xl       = (ushort*)(base + alloc((size_t)MB*64*128*2));
    ushort* xr       = (ushort*)(base + alloc((size_t)MB*64*128*2));
    size_t zoff = o;
    int*    deg_i    = (int*)   (base + alloc((size_t)NP*4));
    int*    cursor   = (int*)   (base + alloc((size_t)NP*4));
    float*  attr_sum = (float*) (base + alloc((size_t)NP*8*4));
    size_t zbytes = o - zoff;
    int*    csr_off  = (int*)   (base + alloc((size_t)NP*4));
    int*    partial  = (int*)   (base + alloc(256*4));
    int*    csr_pack = (int*)   (base + alloc((size_t)E*4));
    unsigned char* etype_e = (unsigned char*)(base + alloc((size_t)E));
    (void)ws_size; (void)n_in; (void)out_size;

    k_twt  <<<128, 256, 0, stream>>>(Wl, Wr, We, Wt, Web, (int*)(base + zoff), (int)(zbytes/4));
    k_gemm <<<MB,  256, 0, stream>>>(x, Wt, bl, br, xl, xr, N);
    k_deg  <<<(E+255)/256, 256, 0, stream>>>(dst, ea, deg_i, attr_sum, etype_e, E);
    k_scan1<<<SB,  256, 0, stream>>>(deg_i, csr_off, partial);
    k_scan2<<<1,   256, 0, stream>>>(partial, SB);
    k_fill <<<(E+255)/256, 256, 0, stream>>>(src, dst, etype_e, cursor, csr_off, partial, csr_pack, E);
    k_node <<<(N+3)/4, 256, 0, stream>>>(deg_i, csr_off, partial, csr_pack, xl, xr, Web, att, attr_sum,
                                         bias, lnw, lnb, out, N);
}

// Round 6
// 229.157 us; speedup vs baseline: 1.1813x; 1.1176x over previous
//
#include <hip/hip_runtime.h>
#include <hip/hip_bf16.h>

typedef _Float16 f16x8 __attribute__((ext_vector_type(8)));
typedef _Float16 h2    __attribute__((ext_vector_type(2)));
typedef float    f32x4v __attribute__((ext_vector_type(4)));
typedef float    f32x2 __attribute__((ext_vector_type(2)));

#define NEG_SLOPE 0.2f

__device__ __forceinline__ ushort f2h_bits(float f){ _Float16 h=(_Float16)f; return __builtin_bit_cast(ushort, h); }
__device__ __forceinline__ h2 uash2(unsigned u){ return __builtin_bit_cast(h2, u); }
__device__ __forceinline__ float lrelu(float v){ return fmaxf(v,0.f) + NEG_SLOPE*fminf(v,0.f); }

// ---------------- K0: prep — Wt[256][128]=[Wl|Wr]^T (f16), Web (f16), att_h (f16), deg/attr/etype ----------------
__global__ __launch_bounds__(256) void k_prep(const float* __restrict__ Wl, const float* __restrict__ Wr,
    const float* __restrict__ We, const float* __restrict__ att,
    ushort* __restrict__ Wt, ushort* __restrict__ Web, ushort* __restrict__ att_h,
    const int* __restrict__ dst, const float* __restrict__ ea,
    int* __restrict__ deg_i, float* __restrict__ attr_sum, unsigned char* __restrict__ etype_e, int E)
{
    int idx = blockIdx.x*256 + threadIdx.x;
    if (idx < 256*128) {
        int c = idx >> 7, k = idx & 127;
        float v = (c < 128) ? Wl[k*128 + c] : Wr[k*128 + (c-128)];
        Wt[idx] = f2h_bits(v);
    }
    if (idx < 8*128) Web[idx] = f2h_bits(We[idx]);
    if (idx < 128)   att_h[idx] = f2h_bits(att[idx]);
    if (idx >= E) return;
    int d = dst[idx];
    atomicAdd(&deg_i[d], 1);
    const float* a = ea + (size_t)idx*8;
    float4 u0 = *(const float4*)a;
    float4 u1 = *(const float4*)(a + 4);
    float v[8] = {u0.x,u0.y,u0.z,u0.w,u1.x,u1.y,u1.z,u1.w};
    float best = 0.f; int bt = 0;                 // one-hot: find the nonzero component
    #pragma unroll
    for (int j=0;j<8;++j)
        if (fabsf(v[j]) > fabsf(best)) { best = v[j]; bt = j; }
    etype_e[idx] = (unsigned char)bt;
    if (best != 0.f) atomicAdd(&attr_sum[(size_t)d*8 + bt], best);
}

// ---------------- K1: single-kernel scan (block scan + atomic base) ----------------
__global__ __launch_bounds__(256) void k_scan(const int* __restrict__ deg_i, int* __restrict__ csr_off,
                                              int* __restrict__ gtotal)
{
    __shared__ int s[256];
    __shared__ int sbase;
    int i = blockIdx.x*256 + threadIdx.x;
    int v = deg_i[i];
    s[threadIdx.x] = v;
    __syncthreads();
    #pragma unroll
    for (int off=1; off<256; off<<=1){
        int t = (threadIdx.x >= off) ? s[threadIdx.x-off] : 0;
        __syncthreads();
        s[threadIdx.x] += t;
        __syncthreads();
    }
    if (threadIdx.x == 255) sbase = atomicAdd(gtotal, s[255]);
    __syncthreads();
    csr_off[i] = s[threadIdx.x] - v + sbase;      // exclusive global offset (segment order arbitrary)
}

// ---------------- K2: fused MFMA GEMM (blocks < MB) + CSR fill (blocks >= MB) ----------------
__global__ __launch_bounds__(256) void k_gemmfill(const float* __restrict__ x, const ushort* __restrict__ Wt,
    const float* __restrict__ bl, const float* __restrict__ br,
    ushort* __restrict__ xl, ushort* __restrict__ xr, int Nn, int MB,
    const int* __restrict__ src, const int* __restrict__ dst, const unsigned char* __restrict__ etype_e,
    int* __restrict__ cursor, const int* __restrict__ csr_off, int* __restrict__ csr_pack, int E)
{
    __shared__ ushort As[64*128];                 // 16KB f16 bits, XOR-swizzled 16B granules
    if ((int)blockIdx.x >= MB) {
        int e = ((int)blockIdx.x - MB)*256 + threadIdx.x;
        if (e < E) {
            int d = dst[e];
            int slot = csr_off[d] + atomicAdd(&cursor[d], 1);
            csr_pack[slot] = src[e] | ((int)etype_e[e] << 24);
        }
        return;
    }
    int tid = threadIdx.x;
    int wave = tid >> 6, lane = tid & 63;
    int l15 = lane & 15, l4 = lane >> 4;
    int row0 = blockIdx.x * 64;

    #pragma unroll
    for (int it = 0; it < 4; ++it) {
        int idx = tid + it*256;                   // granule id (8 cols each), 1024 total
        int r = idx >> 4;
        int g = idx & 15;
        float4 a = make_float4(0,0,0,0), b = make_float4(0,0,0,0);
        int g_row = row0 + r;
        if (g_row < Nn) {
            const float* p = x + (size_t)g_row*128 + g*8;
            a = *(const float4*)p;
            b = *(const float4*)(p + 4);
        }
        union { ushort us[8]; uint4 v; } P;
        P.us[0]=f2h_bits(a.x); P.us[1]=f2h_bits(a.y); P.us[2]=f2h_bits(a.z); P.us[3]=f2h_bits(a.w);
        P.us[4]=f2h_bits(b.x); P.us[5]=f2h_bits(b.y); P.us[6]=f2h_bits(b.z); P.us[7]=f2h_bits(b.w);
        int sw = (g*16) ^ ((r & 7) << 4);
        *(uint4*)((char*)As + r*256 + sw) = P.v;
    }
    __syncthreads();

    f16x8 bfrag[4][4];
    #pragma unroll
    for (int nf = 0; nf < 4; ++nf) {
        int col = wave*64 + nf*16 + l15;
        const ushort* bp = Wt + (size_t)col*128;
        #pragma unroll
        for (int ks = 0; ks < 4; ++ks)
            bfrag[ks][nf] = *(const f16x8*)(const void*)(bp + ks*32 + l4*8);
    }
    f32x4v acc[4][4];
    #pragma unroll
    for (int i=0;i<4;++i)
        #pragma unroll
        for (int j=0;j<4;++j) acc[i][j] = (f32x4v){0.f,0.f,0.f,0.f};

    #pragma unroll
    for (int ks = 0; ks < 4; ++ks) {
        f16x8 afrag[4];
        #pragma unroll
        for (int mf = 0; mf < 4; ++mf) {
            int r = mf*16 + l15;
            int kbyte = ks*64 + l4*16;
            afrag[mf] = *(const f16x8*)(const void*)((char*)As + r*256 + (kbyte ^ ((r&7)<<4)));
        }
        #pragma unroll
        for (int mf = 0; mf < 4; ++mf)
            #pragma unroll
            for (int nf = 0; nf < 4; ++nf)
                acc[mf][nf] = __builtin_amdgcn_mfma_f32_16x16x32_f16(afrag[mf], bfrag[ks][nf], acc[mf][nf], 0,0,0);
    }
    #pragma unroll
    for (int mf = 0; mf < 4; ++mf) {
        #pragma unroll
        for (int nf = 0; nf < 4; ++nf) {
            int col = wave*64 + nf*16 + l15;
            float bias = (col < 128) ? bl[col] : br[col-128];
            #pragma unroll
            for (int r = 0; r < 4; ++r) {
                int row = row0 + mf*16 + l4*4 + r;
                if (row < Nn) {
                    ushort o = f2h_bits(acc[mf][nf][r] + bias);
                    if (col < 128) xl[(size_t)row*128 + col] = o;
                    else           xr[(size_t)row*128 + (col-128)] = o;
                }
            }
        }
    }
}

// ---------------- K3: fused per-node pass, packed f16 math, 4 edges in flight ----------------
// lane: g = lane>>4 (edge slot), l = lane&15 (channels l*8..l*8+7, head l>>1)
__global__ __launch_bounds__(256) void k_node(const int* __restrict__ deg_i, const int* __restrict__ csr_off,
    const int* __restrict__ csr_pack,
    const ushort* __restrict__ xl, const ushort* __restrict__ xr, const ushort* __restrict__ Web,
    const ushort* __restrict__ att_h, const float* __restrict__ att, const float* __restrict__ attr_sum,
    const float* __restrict__ bias, const float* __restrict__ lnw, const float* __restrict__ lnb,
    float* __restrict__ out, int Nn)
{
    int wv = threadIdx.x >> 6, lane = threadIdx.x & 63;
    int n = blockIdx.x*4 + wv;
    if (n >= Nn) return;
    int g = lane >> 4, l = lane & 15;

    h2 xr2[4], at2[4];
    {
        uint4 ru = *(const uint4*)(xr + (size_t)n*128 + l*8);
        uint4 au = *(const uint4*)(att_h + l*8);
        xr2[0]=uash2(ru.x); xr2[1]=uash2(ru.y); xr2[2]=uash2(ru.z); xr2[3]=uash2(ru.w);
        at2[0]=uash2(au.x); at2[1]=uash2(au.y); at2[2]=uash2(au.z); at2[3]=uash2(au.w);
    }
    const h2 z2  = {(_Float16)0.f, (_Float16)0.f};
    const h2 c02 = {(_Float16)NEG_SLOPE, (_Float16)NEG_SLOPE};

    int beg = csr_off[n];
    int cnt = deg_i[n];
    f32x2 acc2[4];
    #pragma unroll
    for (int k=0;k<4;++k) acc2[k] = (f32x2){0.f,0.f};
    float den = 0.f;

    #pragma unroll 2
    for (int i = 0; i < cnt; i += 4) {
        bool valid = (i + g) < cnt;
        int packed = csr_pack[beg + (valid ? i + g : 0)];
        int sidx = packed & 0xFFFFFF;
        int et = ((unsigned)packed) >> 24;
        uint4 xu = *(const uint4*)(xl + (size_t)sidx*128 + l*8);
        uint4 wu = *(const uint4*)(Web + (size_t)et*128 + l*8);
        h2 xs[4] = {uash2(xu.x), uash2(xu.y), uash2(xu.z), uash2(xu.w)};
        h2 ws[4] = {uash2(wu.x), uash2(wu.y), uash2(wu.z), uash2(wu.w)};
        float p = 0.f;
        f32x2 xf[4];
        #pragma unroll
        for (int k=0;k<4;++k){
            h2 v = (xs[k] + xr2[k]) + ws[k];
            h2 r = __builtin_elementwise_max(v, z2);
            h2 m = __builtin_elementwise_min(v, z2);
            r = r + c02*m;                                  // pk_fma
            p = __builtin_amdgcn_fdot2(at2[k], r, p, false);
            xf[k] = __builtin_convertvector(xs[k], f32x2);
        }
        p += __shfl_xor(p, 1);                              // head score (2 lanes/head)
        float ex = valid ? __expf(p) : 0.f;
        den += ex;
        #pragma unroll
        for (int k=0;k<4;++k) acc2[k] += ex * xf[k];
    }

    // cross-edge-group reduce: all 4 groups identical after this
    #pragma unroll
    for (int k=0;k<4;++k){
        acc2[k].x += __shfl_xor(acc2[k].x, 16); acc2[k].x += __shfl_xor(acc2[k].x, 32);
        acc2[k].y += __shfl_xor(acc2[k].y, 16); acc2[k].y += __shfl_xor(acc2[k].y, 32);
    }
    den += __shfl_xor(den, 16);
    den += __shfl_xor(den, 32);

    // self loop (f32 path, once per node)
    {
        f32x2 xsf[4], xrf[4], av[4], emb[4];
        uint4 su = *(const uint4*)(xl + (size_t)n*128 + l*8);
        xsf[0]=__builtin_convertvector(uash2(su.x), f32x2); xsf[1]=__builtin_convertvector(uash2(su.y), f32x2);
        xsf[2]=__builtin_convertvector(uash2(su.z), f32x2); xsf[3]=__builtin_convertvector(uash2(su.w), f32x2);
        #pragma unroll
        for (int k=0;k<4;++k){ xrf[k]=__builtin_convertvector(xr2[k], f32x2); emb[k]=(f32x2){0.f,0.f}; }
        float4 a0 = *(const float4*)(att + l*8);
        float4 a1 = *(const float4*)(att + l*8 + 4);
        av[0]=(f32x2){a0.x,a0.y}; av[1]=(f32x2){a0.z,a0.w}; av[2]=(f32x2){a1.x,a1.y}; av[3]=(f32x2){a1.z,a1.w};
        float inv = 1.f / fmaxf((float)cnt, 1.f);
        #pragma unroll
        for (int t=0;t<8;++t){
            float w = attr_sum[(size_t)n*8 + t] * inv;
            uint4 wu = *(const uint4*)(Web + t*128 + l*8);
            emb[0] += w*__builtin_convertvector(uash2(wu.x), f32x2);
            emb[1] += w*__builtin_convertvector(uash2(wu.y), f32x2);
            emb[2] += w*__builtin_convertvector(uash2(wu.z), f32x2);
            emb[3] += w*__builtin_convertvector(uash2(wu.w), f32x2);
        }
        float p = 0.f;
        #pragma unroll
        for (int k=0;k<4;++k){
            f32x2 v = xsf[k] + xrf[k] + emb[k];
            p += av[k].x*lrelu(v.x) + av[k].y*lrelu(v.y);
        }
        p += __shfl_xor(p, 1);
        float ex = __expf(p);
        den += ex;
        #pragma unroll
        for (int k=0;k<4;++k) acc2[k] += ex * xsf[k];
    }

    float dinv = 1.f/den;
    f32x2 a[4];
    {
        float4 b0 = *(const float4*)(bias + l*8);
        float4 b1 = *(const float4*)(bias + l*8 + 4);
        a[0] = acc2[0]*dinv + (f32x2){b0.x,b0.y};
        a[1] = acc2[1]*dinv + (f32x2){b0.z,b0.w};
        a[2] = acc2[2]*dinv + (f32x2){b1.x,b1.y};
        a[3] = acc2[3]*dinv + (f32x2){b1.z,b1.w};
    }
    float sum = 0.f;
    #pragma unroll
    for (int k=0;k<4;++k) sum += a[k].x + a[k].y;
    #pragma unroll
    for (int off=8; off>0; off>>=1) sum += __shfl_xor(sum, off);
    float mu = sum * (1.f/128.f);
    float vs = 0.f;
    #pragma unroll
    for (int k=0;k<4;++k){ a[k] -= mu; vs += a[k].x*a[k].x + a[k].y*a[k].y; }
    #pragma unroll
    for (int off=8; off>0; off>>=1) vs += __shfl_xor(vs, off);
    float rs = rsqrtf(vs*(1.f/128.f) + 1e-5f);
    float y[8];
    {
        float4 w0 = *(const float4*)(lnw + l*8);
        float4 w1 = *(const float4*)(lnw + l*8 + 4);
        float4 c0 = *(const float4*)(lnb + l*8);
        float4 c1 = *(const float4*)(lnb + l*8 + 4);
        y[0]=a[0].x*rs*w0.x+c0.x; y[1]=a[0].y*rs*w0.y+c0.y;
        y[2]=a[1].x*rs*w0.z+c0.z; y[3]=a[1].y*rs*w0.w+c0.w;
        y[4]=a[2].x*rs*w1.x+c1.x; y[5]=a[2].y*rs*w1.y+c1.y;
        y[6]=a[3].x*rs*w1.z+c1.z; y[7]=a[3].y*rs*w1.w+c1.w;
    }
    #pragma unroll
    for (int j=0;j<8;++j) y[j] = (y[j] > 0.f) ? y[j] : (__expf(y[j]) - 1.f);
    if (lane < 16) {
        float* po = out + (size_t)n*128 + l*8;
        *(float4*)po     = make_float4(y[0],y[1],y[2],y[3]);
        *(float4*)(po+4) = make_float4(y[4],y[5],y[6],y[7]);
    }
}

extern "C" void kernel_launch(void* const* d_in, const int* in_sizes, int n_in,
                              void* d_out, int out_size, void* d_ws, size_t ws_size,
                              hipStream_t stream)
{
    const float* x   = (const float*)d_in[0];
    const int*   src = (const int*)  d_in[1];
    const int*   dst = (const int*)  d_in[2];
    const float* ea  = (const float*)d_in[3];
    const float* Wl  = (const float*)d_in[4];
    const float* bl  = (const float*)d_in[5];
    const float* Wr  = (const float*)d_in[6];
    const float* br  = (const float*)d_in[7];
    const float* We  = (const float*)d_in[8];
    const float* att = (const float*)d_in[9];
    const float* bias= (const float*)d_in[10];
    const float* lnw = (const float*)d_in[11];
    const float* lnb = (const float*)d_in[12];
    float* out = (float*)d_out;

    const int N  = in_sizes[0] / 128;
    const int E  = in_sizes[1];
    const int NP = ((N + 255)/256)*256;
    const int MB = (N + 63)/64;
    const int SB = NP/256;
    const int EB = (E + 255)/256;

    char* base = (char*)d_ws;
    size_t o = 0;
    auto alloc = [&](size_t b){ size_t r = o; o += (b + 255) & ~(size_t)255; return r; };
    ushort* Wt       = (ushort*)(base + alloc(256*128*2));
    ushort* Web      = (ushort*)(base + alloc(8*128*2));
    ushort* att_h    = (ushort*)(base + alloc(128*2));
    ushort* xl       = (ushort*)(base + alloc((size_t)MB*64*128*2));
    ushort* xr       = (ushort*)(base + alloc((size_t)MB*64*128*2));
    size_t zoff = o;
    int*    deg_i    = (int*)   (base + alloc((size_t)NP*4));
    int*    cursor   = (int*)   (base + alloc((size_t)NP*4));
    float*  attr_sum = (float*) (base + alloc((size_t)NP*8*4));
    int*    gtotal   = (int*)   (base + alloc(256));
    size_t zbytes = o - zoff;
    int*    csr_off  = (int*)   (base + alloc((size_t)NP*4));
    int*    csr_pack = (int*)   (base + alloc((size_t)E*4));
    unsigned char* etype_e = (unsigned char*)(base + alloc((size_t)E));
    (void)ws_size; (void)n_in; (void)out_size;

    hipMemsetAsync(base + zoff, 0, zbytes, stream);
    k_prep    <<<EB, 256, 0, stream>>>(Wl, Wr, We, att, Wt, Web, att_h, dst, ea, deg_i, attr_sum, etype_e, E);
    k_scan    <<<SB, 256, 0, stream>>>(deg_i, csr_off, gtotal);
    k_gemmfill<<<MB+EB, 256, 0, stream>>>(x, Wt, bl, br, xl, xr, N, MB, src, dst, etype_e, cursor, csr_off, csr_pack, E);
    k_node    <<<(N+3)/4, 256, 0, stream>>>(deg_i, csr_off, csr_pack, xl, xr, Web, att_h, att, attr_sum,
                                            bias, lnw, lnb, out, N);
}